// Round 1
// baseline (903.621 us; speedup 1.0000x reference)
//
#include <hip/hip_runtime.h>
#include <hip/hip_bf16.h>
#include <math.h>

#define ALPHA 0.01f

// ---------------------------------------------------------------------------
// Fused layer kernel: Y = leaky_relu(X @ W^T + b), plus per-row histogram
// entropy (bins = DOUT) accumulated (sum over rows) into *Hacc via atomicAdd.
//
// Block = 256 threads. Each block computes R rows x all DOUT cols.
// Thread (tc, tr) owns CPT cols x RPT rows of the output tile.
//   CT = DOUT/CPT col-threads, RT = R/RPT row-threads, CT*RT == 256.
// K is tiled by KT=16; X tile stored transposed in LDS (Xl[k][r]),
// W tile transposed into Wl[k][c] so inner loop reads are contiguous.
// ---------------------------------------------------------------------------
template <int DIN, int DOUT, int R, int CPT, int RPT>
__global__ __launch_bounds__(256) void layer_kernel(
    const float* __restrict__ X, const float* __restrict__ W,
    const float* __restrict__ b, float* __restrict__ Y,
    float* __restrict__ Hacc)
{
    constexpr int CT = DOUT / CPT;
    constexpr int RT = R / RPT;
    static_assert(CT * RT == 256, "bad thread config");
    static_assert(CPT == 4, "CPT must be 4 (float4 paths)");
    constexpr int KT = 16;
    static_assert(DIN % KT == 0, "DIN % KT");
    constexpr int BINS = DOUT;
    constexpr int XE = (R * KT) / 256;   // X-stage elements per thread
    static_assert((R * KT) % 256 == 0, "XE");

    // LDS: staging area (Xl + Wl) reused as the output tile (Ol) afterwards.
    constexpr int SM_STAGE = KT * (R + DOUT) * (int)sizeof(float);
    constexpr int SM_HIST  = R * DOUT * (int)sizeof(float);
    constexpr int SM_MAIN  = SM_STAGE > SM_HIST ? SM_STAGE : SM_HIST;
    __shared__ __align__(16) char smem[SM_MAIN];
    float (*Xl)[R]    = reinterpret_cast<float (*)[R]>(smem);
    float (*Wl)[DOUT] = reinterpret_cast<float (*)[DOUT]>(smem + KT * R * sizeof(float));
    float (*Ol)[DOUT] = reinterpret_cast<float (*)[DOUT]>(smem);
    __shared__ int   counts[4][BINS];   // per-wave private histograms
    __shared__ float Hblk;

    const int t  = threadIdx.x;
    const int tc = t % CT;
    const int tr = t / CT;
    const int row0 = blockIdx.x * R;

    float acc[RPT][CPT];
    {
        float4 bb = *reinterpret_cast<const float4*>(b + tc * CPT);
        #pragma unroll
        for (int j = 0; j < RPT; j++) {
            acc[j][0] = bb.x; acc[j][1] = bb.y; acc[j][2] = bb.z; acc[j][3] = bb.w;
        }
    }

    for (int k0 = 0; k0 < DIN; k0 += KT) {
        __syncthreads();   // protect previous iter's LDS reads
        // stage X tile (transposed): Xl[k][r] = X[row0+r][k0+k]
        #pragma unroll
        for (int i = 0; i < XE; i++) {
            int e = t + i * 256;
            int r = e / KT, k = e % KT;
            Xl[k][r] = X[(size_t)(row0 + r) * DIN + (k0 + k)];
        }
        // stage W tile (transposed): Wl[k][c] = W[c][k0+k]
        if (t < DOUT) {
            const float* wp = W + (size_t)t * DIN + k0;
            #pragma unroll
            for (int j = 0; j < KT / 4; j++) {
                float4 wv = *reinterpret_cast<const float4*>(wp + 4 * j);
                Wl[4 * j + 0][t] = wv.x;
                Wl[4 * j + 1][t] = wv.y;
                Wl[4 * j + 2][t] = wv.z;
                Wl[4 * j + 3][t] = wv.w;
            }
        }
        __syncthreads();

        #pragma unroll
        for (int k = 0; k < KT; k++) {
            float xv[RPT], wv[CPT];
            #pragma unroll
            for (int j = 0; j < RPT; j++) xv[j] = Xl[k][tr * RPT + j];
            #pragma unroll
            for (int c = 0; c < CPT; c++) wv[c] = Wl[k][tc * CPT + c];
            #pragma unroll
            for (int j = 0; j < RPT; j++)
                #pragma unroll
                for (int c = 0; c < CPT; c++)
                    acc[j][c] = fmaf(xv[j], wv[c], acc[j][c]);
        }
    }

    __syncthreads();   // all LDS stage reads done; smem becomes Ol

    // leaky_relu, write to global and to LDS output tile
    #pragma unroll
    for (int j = 0; j < RPT; j++) {
        int r = tr * RPT + j;
        float4 v;
        float a0 = acc[j][0], a1 = acc[j][1], a2 = acc[j][2], a3 = acc[j][3];
        v.x = a0 > 0.0f ? a0 : ALPHA * a0;
        v.y = a1 > 0.0f ? a1 : ALPHA * a1;
        v.z = a2 > 0.0f ? a2 : ALPHA * a2;
        v.w = a3 > 0.0f ? a3 : ALPHA * a3;
        *reinterpret_cast<float4*>(&Ol[r][tc * CPT]) = v;
        *reinterpret_cast<float4*>(Y + (size_t)(row0 + r) * DOUT + tc * CPT) = v;
    }
    __syncthreads();

    // ---- per-row histogram entropy: wave w handles rows [w*R/4, (w+1)*R/4)
    const int wave = t >> 6;
    const int lane = t & 63;
    float Hw = 0.0f;

    #pragma unroll 1
    for (int i = 0; i < R / 4; i++) {
        int r = wave * (R / 4) + i;
        // row min/max
        float mn = 1e30f, mx = -1e30f;
        for (int c = lane; c < DOUT; c += 64) {
            float v = Ol[r][c];
            mn = fminf(mn, v);
            mx = fmaxf(mx, v);
        }
        #pragma unroll
        for (int off = 32; off > 0; off >>= 1) {
            mn = fminf(mn, __shfl_xor(mn, off, 64));
            mx = fmaxf(mx, __shfl_xor(mx, off, 64));
        }
        float wdt = mx - mn;
        float sw  = (wdt > 0.0f) ? wdt : 1.0f;

        // zero this wave's histogram (LDS ops are in-order within a wave)
        for (int c = lane; c < BINS; c += 64) counts[wave][c] = 0;

        // bin: idx = clip(floor((x-mn)/sw * BINS), 0, BINS-1)
        for (int c = lane; c < DOUT; c += 64) {
            float tt = (Ol[r][c] - mn) / sw * (float)BINS;
            int idx = (int)tt;              // tt >= 0 so trunc == floor
            idx = idx < (BINS - 1) ? idx : (BINS - 1);
            idx = idx > 0 ? idx : 0;
            atomicAdd(&counts[wave][idx], 1);
        }
        __threadfence_block();

        // entropy: H = -sum p log p + log(BINS)
        float s = 0.0f;
        for (int c = lane; c < BINS; c += 64) {
            int cnt = counts[wave][c];
            if (cnt > 0) {
                float p = (float)cnt * (1.0f / (float)DOUT);
                s += p * __logf(p);
            }
        }
        #pragma unroll
        for (int off = 32; off > 0; off >>= 1) s += __shfl_xor(s, off, 64);
        if (lane == 0) Hw += (-s + logf((float)BINS));
    }

    if (t == 0) Hblk = 0.0f;
    __syncthreads();
    if (lane == 0) atomicAdd(&Hblk, Hw);
    __syncthreads();
    if (t == 0) atomicAdd(Hacc, Hblk);
}

// ---------------------------------------------------------------------------
// Layer 6: out = log_softmax(relu(X @ W6^T + b6)); X: [B,32], W6: [10,32]
// One thread per row.
// ---------------------------------------------------------------------------
__global__ __launch_bounds__(256) void layer6_kernel(
    const float* __restrict__ X, const float* __restrict__ W,
    const float* __restrict__ b, float* __restrict__ out)
{
    __shared__ float Wl[320];
    __shared__ float bl[10];
    const int t = threadIdx.x;
    for (int i = t; i < 320; i += 256) Wl[i] = W[i];
    if (t < 10) bl[t] = b[t];
    __syncthreads();

    const size_t row = (size_t)blockIdx.x * 256 + t;
    float x[32];
    const float4* xp = reinterpret_cast<const float4*>(X + row * 32);
    #pragma unroll
    for (int i = 0; i < 8; i++) {
        float4 v = xp[i];
        x[4 * i + 0] = v.x; x[4 * i + 1] = v.y;
        x[4 * i + 2] = v.z; x[4 * i + 3] = v.w;
    }

    float z[10];
    float m = -1e30f;
    #pragma unroll
    for (int j = 0; j < 10; j++) {
        float s = bl[j];
        #pragma unroll
        for (int k = 0; k < 32; k++) s = fmaf(x[k], Wl[j * 32 + k], s);
        z[j] = fmaxf(s, 0.0f);
        m = fmaxf(m, z[j]);
    }
    float se = 0.0f;
    #pragma unroll
    for (int j = 0; j < 10; j++) se += expf(z[j] - m);
    float ls = logf(se);
    float* op = out + row * 10;
    #pragma unroll
    for (int j = 0; j < 10; j++) op[j] = z[j] - m - ls;
}

__global__ void finalize_kernel(const float* __restrict__ Hacc,
                                float* __restrict__ out_tail)
{
    int t = threadIdx.x;
    if (t < 5) out_tail[t] = Hacc[t] * (1.0f / 65536.0f);
}

// ---------------------------------------------------------------------------
extern "C" void kernel_launch(void* const* d_in, const int* in_sizes, int n_in,
                              void* d_out, int out_size, void* d_ws, size_t ws_size,
                              hipStream_t stream)
{
    const float* x  = (const float*)d_in[0];
    const float* W1 = (const float*)d_in[1];  const float* b1 = (const float*)d_in[2];
    const float* W2 = (const float*)d_in[3];  const float* b2 = (const float*)d_in[4];
    const float* W3 = (const float*)d_in[5];  const float* b3 = (const float*)d_in[6];
    const float* W4 = (const float*)d_in[7];  const float* b4 = (const float*)d_in[8];
    const float* W5 = (const float*)d_in[9];  const float* b5 = (const float*)d_in[10];
    const float* W6 = (const float*)d_in[11]; const float* b6 = (const float*)d_in[12];
    float* out = (float*)d_out;

    constexpr int B = 65536;
    char* ws = (char*)d_ws;
    float* H    = (float*)ws;                                   // 5 floats
    float* bufA = (float*)(ws + 256);                           // up to B*256 f32
    float* bufB = (float*)(ws + 256 + (size_t)B * 256 * 4);     // up to B*128 f32

    hipMemsetAsync(H, 0, 5 * sizeof(float), stream);

    layer_kernel<784, 256, 32, 4, 8><<<B / 32, 256, 0, stream>>>(x,    W1, b1, bufA, H + 0);
    layer_kernel<256, 128, 32, 4, 4><<<B / 32, 256, 0, stream>>>(bufA, W2, b2, bufB, H + 1);
    layer_kernel<128, 128, 32, 4, 4><<<B / 32, 256, 0, stream>>>(bufB, W3, b3, bufA, H + 2);
    layer_kernel<128, 128, 32, 4, 4><<<B / 32, 256, 0, stream>>>(bufA, W4, b4, bufB, H + 3);
    layer_kernel<128,  32, 64, 4, 2><<<B / 64, 256, 0, stream>>>(bufB, W5, b5, bufA, H + 4);

    layer6_kernel<<<B / 256, 256, 0, stream>>>(bufA, W6, b6, out);
    finalize_kernel<<<1, 64, 0, stream>>>(H, out + (size_t)B * 10);
}

// Round 2
// 684.448 us; speedup vs baseline: 1.3202x; 1.3202x over previous
//
#include <hip/hip_runtime.h>
#include <hip/hip_bf16.h>
#include <math.h>

#define ALPHA 0.01f

typedef __bf16 bf16x8 __attribute__((ext_vector_type(8)));
typedef float  floatx4 __attribute__((ext_vector_type(4)));

static __device__ __forceinline__ unsigned short f2bf_bits(float f) {
    return __builtin_bit_cast(unsigned short, (__bf16)f);   // RNE
}
static __device__ __forceinline__ float bf2f(unsigned short u) {
    return __builtin_bit_cast(float, (unsigned)u << 16);    // exact
}

// ---------------------------------------------------------------------------
// MFMA layer: Y(bf16) = leaky_relu(X @ W^T + b); per-row histogram entropy
// (bins = DOUT) summed into *Hacc. Block = 256 thr (4 waves) x 128 rows x DOUT.
// Wave w computes rows [w*32, w*32+32) over all DOUT cols via 16x16x32 bf16
// MFMA. LDS tiles: A [128][32] bf16 stride 40 elems (80 B: 2-way bank = free),
// W [DOUT][32] bf16 stride 40. Out tile overlays staging: bf16, stride DOUT+4.
// ---------------------------------------------------------------------------
template <int DIN, int DOUT, bool XF32>
__global__ __launch_bounds__(256, 2) void layer_mfma(
    const void* __restrict__ Xin, const unsigned short* __restrict__ Wb,
    const float* __restrict__ bias, unsigned short* __restrict__ Y,
    float* __restrict__ Hacc)
{
    constexpr int RT   = 128;               // rows per block
    constexpr int CTN  = DOUT / 16;         // col tiles per wave
    constexpr int KTN  = (DIN + 31) / 32;   // k tiles (L1 has 16-wide tail)
    constexpr int OSTRIDE = DOUT + 4;       // out tile stride (elems)
    constexpr int ABYTES = RT * 80;         // A tile bytes (stride 40 bf16)
    constexpr int WBYTES = DOUT * 80;
    constexpr int STAGEB = ABYTES + WBYTES;
    constexpr int OUTB   = RT * OSTRIDE * 2;
    constexpr int SMB    = STAGEB > OUTB ? STAGEB : OUTB;
    static_assert(DOUT % 16 == 0 && DOUT <= 256, "DOUT");
    static_assert(DIN % 4 == 0, "DIN");

    __shared__ __align__(16) char smem[SMB];
    __shared__ int   counts[4][DOUT];
    __shared__ float biasl[DOUT];

    const int t      = threadIdx.x;
    const int lane   = t & 63;
    const int lane16 = lane & 15;
    const int q      = lane >> 4;
    const int w      = t >> 6;
    const int row0   = blockIdx.x * RT;

    if (t < DOUT) biasl[t] = bias[t];

    floatx4 acc[2][CTN];
    #pragma unroll
    for (int rt = 0; rt < 2; rt++)
        #pragma unroll
        for (int ct = 0; ct < CTN; ct++) acc[rt][ct] = (floatx4)(0.0f);

    for (int kt = 0; kt < KTN; kt++) {
        const int k0 = kt * 32;
        __syncthreads();
        // ---- stage A tile [128 rows][32 k]
        if constexpr (XF32) {
            const float* X = (const float*)Xin;
            #pragma unroll
            for (int i = 0; i < 4; i++) {
                int e = t + i * 256;            // 1024 chunks of 4
                int r = e >> 3, c = e & 7;
                int k = k0 + c * 4;
                float4 v = make_float4(0.f, 0.f, 0.f, 0.f);
                if (k < DIN) v = *(const float4*)(X + (size_t)(row0 + r) * DIN + k);
                uint2 p;
                p.x = (unsigned)f2bf_bits(v.x) | ((unsigned)f2bf_bits(v.y) << 16);
                p.y = (unsigned)f2bf_bits(v.z) | ((unsigned)f2bf_bits(v.w) << 16);
                *(uint2*)(smem + r * 80 + c * 8) = p;
            }
        } else {
            const unsigned short* X = (const unsigned short*)Xin;
            #pragma unroll
            for (int i = 0; i < 2; i++) {
                int e = t + i * 256;            // 512 chunks of 8
                int r = e >> 2, c = e & 3;
                uint4 v = *(const uint4*)(X + (size_t)(row0 + r) * DIN + k0 + c * 8);
                *(uint4*)(smem + r * 80 + c * 16) = v;
            }
        }
        // ---- stage W tile [DOUT][32 k] (bf16 source)
        #pragma unroll
        for (int i = 0; i < DOUT / 32; i++) {
            int e = t + i * 256;                // DOUT*8 chunks of 4
            int r = e >> 3, c = e & 7;
            int k = k0 + c * 4;
            uint2 v = make_uint2(0u, 0u);
            if (k < DIN) v = *(const uint2*)(Wb + (size_t)r * DIN + k);
            *(uint2*)(smem + ABYTES + r * 80 + c * 8) = v;
        }
        __syncthreads();

        // ---- fragments + MFMA
        bf16x8 a0 = *(const bf16x8*)(smem + (w * 32 + lane16) * 80 + q * 16);
        bf16x8 a1 = *(const bf16x8*)(smem + (w * 32 + 16 + lane16) * 80 + q * 16);
        #pragma unroll
        for (int ct = 0; ct < CTN; ct++) {
            bf16x8 bf = *(const bf16x8*)(smem + ABYTES + (ct * 16 + lane16) * 80 + q * 16);
            acc[0][ct] = __builtin_amdgcn_mfma_f32_16x16x32_bf16(a0, bf, acc[0][ct], 0, 0, 0);
            acc[1][ct] = __builtin_amdgcn_mfma_f32_16x16x32_bf16(a1, bf, acc[1][ct], 0, 0, 0);
        }
    }

    __syncthreads();    // staging reads done; smem becomes out tile
    unsigned short* Ol = (unsigned short*)smem;

    // ---- epilogue: bias + leaky_relu -> bf16 LDS tile
    // C/D layout: n(col)=lane&15, m(row)=q*4+reg  [verified m89/m91]
    #pragma unroll
    for (int rt = 0; rt < 2; rt++)
        #pragma unroll
        for (int ct = 0; ct < CTN; ct++) {
            int col = ct * 16 + lane16;
            float bb = biasl[col];
            #pragma unroll
            for (int reg = 0; reg < 4; reg++) {
                float v = acc[rt][ct][reg] + bb;
                v = v > 0.0f ? v : ALPHA * v;
                int row = w * 32 + rt * 16 + q * 4 + reg;
                Ol[row * OSTRIDE + col] = f2bf_bits(v);
            }
        }
    __syncthreads();

    // ---- coalesced global write of Y (bf16)
    {
        constexpr int C4 = DOUT / 4;
        #pragma unroll
        for (int i = 0; i < RT * C4 / 256; i++) {
            int e = t + i * 256;
            int r = e / C4, c = e % C4;
            uint2 v = *(const uint2*)(smem + r * (OSTRIDE * 2) + c * 8);
            *(uint2*)(Y + (size_t)(row0 + r) * DOUT + c * 4) = v;
        }
    }

    // ---- per-row histogram entropy; wave w handles its own 32 rows
    float Hw = 0.0f;
    #pragma unroll 1
    for (int i = 0; i < 32; i++) {
        int r = w * 32 + i;
        float mn = 1e30f, mx = -1e30f;
        for (int c = lane; c < DOUT; c += 64) {
            float v = bf2f(Ol[r * OSTRIDE + c]);
            mn = fminf(mn, v); mx = fmaxf(mx, v);
        }
        #pragma unroll
        for (int off = 32; off > 0; off >>= 1) {
            mn = fminf(mn, __shfl_xor(mn, off, 64));
            mx = fmaxf(mx, __shfl_xor(mx, off, 64));
        }
        float wdt = mx - mn;
        float sw  = (wdt > 0.0f) ? wdt : 1.0f;
        float scale = (float)DOUT / sw;

        for (int c = lane; c < DOUT; c += 64) counts[w][c] = 0;

        for (int c = lane; c < DOUT; c += 64) {
            float v = bf2f(Ol[r * OSTRIDE + c]);
            int idx = (int)((v - mn) * scale);
            idx = idx < (DOUT - 1) ? idx : (DOUT - 1);
            idx = idx > 0 ? idx : 0;
            atomicAdd(&counts[w][idx], 1);
        }
        __threadfence_block();

        float s = 0.0f;
        for (int c = lane; c < DOUT; c += 64) {
            int cnt = counts[w][c];
            if (cnt > 0) {
                float p = (float)cnt * (1.0f / (float)DOUT);
                s += p * __logf(p);
            }
        }
        #pragma unroll
        for (int off = 32; off > 0; off >>= 1) s += __shfl_xor(s, off, 64);
        if (lane == 0) Hw += (-s + logf((float)DOUT));
    }
    if (lane == 0) atomicAdd(Hacc, Hw);
}

// ---------------------------------------------------------------------------
// fp32 W1..W5 -> bf16, concatenated into ws
// ---------------------------------------------------------------------------
__global__ void convert_weights(const float* __restrict__ W1, const float* __restrict__ W2,
                                const float* __restrict__ W3, const float* __restrict__ W4,
                                const float* __restrict__ W5, unsigned short* __restrict__ out)
{
    constexpr int s1 = 784 * 256, s2 = 256 * 128, s3 = 128 * 128, s4 = 128 * 128, s5 = 128 * 32;
    int idx = blockIdx.x * 256 + threadIdx.x;
    if (idx >= s1 + s2 + s3 + s4 + s5) return;
    float v;
    if      (idx < s1)                v = W1[idx];
    else if (idx < s1 + s2)           v = W2[idx - s1];
    else if (idx < s1 + s2 + s3)      v = W3[idx - s1 - s2];
    else if (idx < s1 + s2 + s3 + s4) v = W4[idx - s1 - s2 - s3];
    else                              v = W5[idx - s1 - s2 - s3 - s4];
    out[idx] = f2bf_bits(v);
}

// ---------------------------------------------------------------------------
// Layer 6: out = log_softmax(relu(X @ W6^T + b6)); X bf16 [B,32], one thr/row
// ---------------------------------------------------------------------------
__global__ __launch_bounds__(256) void layer6_kernel(
    const unsigned short* __restrict__ Xb, const float* __restrict__ W,
    const float* __restrict__ b, float* __restrict__ out)
{
    __shared__ float Wl[320];
    __shared__ float bl[10];
    const int t = threadIdx.x;
    for (int i = t; i < 320; i += 256) Wl[i] = W[i];
    if (t < 10) bl[t] = b[t];
    __syncthreads();

    const size_t row = (size_t)blockIdx.x * 256 + t;
    float x[32];
    const uint4* xp = (const uint4*)(Xb + row * 32);
    #pragma unroll
    for (int i = 0; i < 4; i++) {
        uint4 v = xp[i];
        unsigned u[4] = {v.x, v.y, v.z, v.w};
        #pragma unroll
        for (int j = 0; j < 4; j++) {
            x[8 * i + 2 * j]     = bf2f((unsigned short)(u[j] & 0xffffu));
            x[8 * i + 2 * j + 1] = bf2f((unsigned short)(u[j] >> 16));
        }
    }

    float z[10];
    float m = -1e30f;
    #pragma unroll
    for (int j = 0; j < 10; j++) {
        float s = bl[j];
        #pragma unroll
        for (int k = 0; k < 32; k++) s = fmaf(x[k], Wl[j * 32 + k], s);
        z[j] = fmaxf(s, 0.0f);
        m = fmaxf(m, z[j]);
    }
    float se = 0.0f;
    #pragma unroll
    for (int j = 0; j < 10; j++) se += expf(z[j] - m);
    float ls = logf(se);
    float* op = out + row * 10;
    #pragma unroll
    for (int j = 0; j < 10; j++) op[j] = z[j] - m - ls;
}

__global__ void finalize_kernel(const float* __restrict__ Hacc,
                                float* __restrict__ out_tail)
{
    int t = threadIdx.x;
    if (t < 5) out_tail[t] = Hacc[t] * (1.0f / 65536.0f);
}

// ---------------------------------------------------------------------------
extern "C" void kernel_launch(void* const* d_in, const int* in_sizes, int n_in,
                              void* d_out, int out_size, void* d_ws, size_t ws_size,
                              hipStream_t stream)
{
    const float* x  = (const float*)d_in[0];
    const float* W1 = (const float*)d_in[1];  const float* b1 = (const float*)d_in[2];
    const float* W2 = (const float*)d_in[3];  const float* b2 = (const float*)d_in[4];
    const float* W3 = (const float*)d_in[5];  const float* b3 = (const float*)d_in[6];
    const float* W4 = (const float*)d_in[7];  const float* b4 = (const float*)d_in[8];
    const float* W5 = (const float*)d_in[9];  const float* b5 = (const float*)d_in[10];
    const float* W6 = (const float*)d_in[11]; const float* b6 = (const float*)d_in[12];
    float* out = (float*)d_out;

    constexpr int B = 65536;
    char* ws = (char*)d_ws;
    float* H = (float*)ws;                                  // 5 floats @ 0
    unsigned short* Wcat = (unsigned short*)(ws + 256);
    unsigned short* W1b = Wcat;                              // 784*256
    unsigned short* W2b = W1b + 784 * 256;                   // 256*128
    unsigned short* W3b = W2b + 256 * 128;                   // 128*128
    unsigned short* W4b = W3b + 128 * 128;                   // 128*128
    unsigned short* W5b = W4b + 128 * 128;                   // 128*32
    unsigned short* bufA = (unsigned short*)(ws + 541184);             // B*256 bf16
    unsigned short* bufB = (unsigned short*)(ws + 541184 + (size_t)B * 256 * 2);

    hipMemsetAsync(H, 0, 5 * sizeof(float), stream);
    convert_weights<<<1056, 256, 0, stream>>>(W1, W2, W3, W4, W5, Wcat);

    layer_mfma<784, 256, true ><<<B / 128, 256, 0, stream>>>(x,    W1b, b1, bufA, H + 0);
    layer_mfma<256, 128, false><<<B / 128, 256, 0, stream>>>(bufA, W2b, b2, bufB, H + 1);
    layer_mfma<128, 128, false><<<B / 128, 256, 0, stream>>>(bufB, W3b, b3, bufA, H + 2);
    layer_mfma<128, 128, false><<<B / 128, 256, 0, stream>>>(bufA, W4b, b4, bufB, H + 3);
    layer_mfma<128,  32, false><<<B / 128, 256, 0, stream>>>(bufB, W5b, b5, bufA, H + 4);

    layer6_kernel<<<B / 256, 256, 0, stream>>>(bufA, W6, b6, out);
    finalize_kernel<<<1, 64, 0, stream>>>(H, out + (size_t)B * 10);
}

// Round 3
// 676.850 us; speedup vs baseline: 1.3350x; 1.0112x over previous
//
#include <hip/hip_runtime.h>
#include <hip/hip_bf16.h>
#include <math.h>

#define ALPHA 0.01f

typedef __bf16 bf16x8 __attribute__((ext_vector_type(8)));
typedef float  floatx4 __attribute__((ext_vector_type(4)));

static __device__ __forceinline__ unsigned short f2bf_bits(float f) {
    return __builtin_bit_cast(unsigned short, (__bf16)f);   // RNE
}
static __device__ __forceinline__ float bf2f(unsigned short u) {
    return __builtin_bit_cast(float, (unsigned)u << 16);    // exact
}

// ---------------------------------------------------------------------------
// MFMA layer: Y(bf16) = leaky_relu(X @ W^T + b); per-row histogram entropy
// (bins = DOUT) summed into *Hacc.
//
// Block = 256 thr (4 waves) x RT=64 rows x full DOUT. Wave w owns rows
// [w*16, w*16+16). 16x16x32 bf16 MFMA; CTN = DOUT/16 col tiles, acc[CTN].
// LDS: A [64][32] bf16 stride 40 elems (80 B -> 2-way bank = free),
//      W [DOUT][32] stride 40. No out-tile: epilogue + entropy run from the
// accumulator registers. C/D layout col=lane&15, row=q*4+reg (verified R2),
// so quad-group q owns rows q*4+reg -> 4 rows processed concurrently per
// wave; per-row reductions are 4-step 16-lane butterflies.
// Histogram: packed 2x u16 bins per u32 LDS word (count <= DOUT < 2^16,
// so atomicAdd(1<<16k) cannot carry across fields).
// ---------------------------------------------------------------------------
template <int DIN, int DOUT, bool XF32, int MINB>
__global__ __launch_bounds__(256, MINB) void layer_mfma(
    const void* __restrict__ Xin, const unsigned short* __restrict__ Wb,
    const float* __restrict__ bias, unsigned short* __restrict__ Y,
    float* __restrict__ Hacc)
{
    constexpr int RT  = 64;
    constexpr int CTN = DOUT / 16;
    constexpr int KTN = (DIN + 31) / 32;
    constexpr int ABYTES = RT * 80;
    constexpr int WBYTES = DOUT * 80;
    constexpr float LOGB = (DOUT == 256) ? 5.54517744f
                         : (DOUT == 128) ? 4.85203026f
                         :                 3.46573590f;   // log(DOUT)
    static_assert(DOUT % 32 == 0 && DOUT <= 256, "DOUT");

    __shared__ __align__(16) char smem[ABYTES + WBYTES];
    __shared__ unsigned int counts[4][4][DOUT / 2];
    __shared__ float biasl[DOUT];

    const int t      = threadIdx.x;
    const int lane   = t & 63;
    const int lane16 = lane & 15;
    const int q      = lane >> 4;
    const int w      = t >> 6;
    const int row0   = blockIdx.x * RT;

    if (t < DOUT) biasl[t] = bias[t];

    floatx4 acc[CTN];
    #pragma unroll
    for (int ct = 0; ct < CTN; ct++) acc[ct] = (floatx4)(0.0f);

    for (int kt = 0; kt < KTN; kt++) {
        const int k0 = kt * 32;
        __syncthreads();
        // ---- stage A tile [64 rows][32 k]
        if constexpr (XF32) {
            const float* X = (const float*)Xin;
            #pragma unroll
            for (int i = 0; i < 2; i++) {
                int e = t + i * 256;            // 512 chunks of 4 floats
                int r = e >> 3, c = e & 7;
                int k = k0 + c * 4;
                float4 v = make_float4(0.f, 0.f, 0.f, 0.f);
                if (DIN % 32 == 0 || k < DIN)
                    v = *(const float4*)(X + (size_t)(row0 + r) * DIN + k);
                uint2 p;
                p.x = (unsigned)f2bf_bits(v.x) | ((unsigned)f2bf_bits(v.y) << 16);
                p.y = (unsigned)f2bf_bits(v.z) | ((unsigned)f2bf_bits(v.w) << 16);
                *(uint2*)(smem + r * 80 + c * 8) = p;
            }
        } else {
            const unsigned short* X = (const unsigned short*)Xin;
            int r = t >> 2, c = t & 3;          // 256 chunks of 8 bf16
            uint4 v = *(const uint4*)(X + (size_t)(row0 + r) * DIN + k0 + c * 8);
            *(uint4*)(smem + r * 80 + c * 16) = v;
        }
        // ---- stage W tile [DOUT][32 k]
        #pragma unroll
        for (int i = 0; i < DOUT / 32; i++) {
            int e = t + i * 256;                // DOUT*8 chunks of 4 bf16
            int r = e >> 3, c = e & 7;
            int k = k0 + c * 4;
            uint2 v = make_uint2(0u, 0u);
            if (DIN % 32 == 0 || k < DIN)
                v = *(const uint2*)(Wb + (size_t)r * DIN + k);
            *(uint2*)(smem + ABYTES + r * 80 + c * 8) = v;
        }
        __syncthreads();

        // ---- fragments + MFMA
        bf16x8 a0 = *(const bf16x8*)(smem + (w * 16 + lane16) * 80 + q * 16);
        const char* wbase = smem + ABYTES + lane16 * 80 + q * 16;
        #pragma unroll
        for (int ct = 0; ct < CTN; ct++) {
            bf16x8 bf = *(const bf16x8*)(wbase + ct * 16 * 80);
            acc[ct] = __builtin_amdgcn_mfma_f32_16x16x32_bf16(a0, bf, acc[ct], 0, 0, 0);
        }
    }

    // ---- epilogue: bias + leaky_relu in registers; direct bf16 stores
    #pragma unroll
    for (int ct = 0; ct < CTN; ct++) {
        float bb = biasl[ct * 16 + lane16];
        #pragma unroll
        for (int reg = 0; reg < 4; reg++) {
            float v = acc[ct][reg] + bb;
            v = v > 0.0f ? v : ALPHA * v;
            acc[ct][reg] = v;
            Y[(size_t)(row0 + w * 16 + q * 4 + reg) * DOUT + ct * 16 + lane16] = f2bf_bits(v);
        }
    }

    // ---- entropy: quad-group q processes its 4 rows (reg = 0..3)
    unsigned int* cc = &counts[w][q][0];
    float Hw = 0.0f;
    #pragma unroll
    for (int reg = 0; reg < 4; reg++) {
        float mn = acc[0][reg], mx = mn;
        #pragma unroll
        for (int ct = 1; ct < CTN; ct++) {
            mn = fminf(mn, acc[ct][reg]);
            mx = fmaxf(mx, acc[ct][reg]);
        }
        #pragma unroll
        for (int off = 1; off <= 8; off <<= 1) {
            mn = fminf(mn, __shfl_xor(mn, off, 64));
            mx = fmaxf(mx, __shfl_xor(mx, off, 64));
        }
        float wdt = mx - mn;
        float scale = (float)DOUT / (wdt > 0.0f ? wdt : 1.0f);

        #pragma unroll
        for (int i = 0; i < DOUT / 32; i++) cc[lane16 + i * 16] = 0u;
        // in-wave LDS program order: zeros precede atomics

        #pragma unroll
        for (int ct = 0; ct < CTN; ct++) {
            int idx = (int)((acc[ct][reg] - mn) * scale);
            idx = idx < (DOUT - 1) ? idx : (DOUT - 1);
            atomicAdd(&cc[idx >> 1], 1u << ((idx & 1) * 16));
        }
        __threadfence_block();

        float s = 0.0f;
        #pragma unroll
        for (int i = 0; i < DOUT / 32; i++) {
            unsigned int word = cc[lane16 + i * 16];
            int c0 = (int)(word & 0xffffu), c1 = (int)(word >> 16);
            if (c0 > 0) { float p = (float)c0 * (1.0f / (float)DOUT); s += p * __logf(p); }
            if (c1 > 0) { float p = (float)c1 * (1.0f / (float)DOUT); s += p * __logf(p); }
        }
        #pragma unroll
        for (int off = 1; off <= 8; off <<= 1) s += __shfl_xor(s, off, 64);
        Hw += LOGB - s;
    }
    // sum the 4 quad-groups (lanes differ only in bits 4/5 across q)
    Hw += __shfl_xor(Hw, 16, 64);
    Hw += __shfl_xor(Hw, 32, 64);
    if (lane == 0) atomicAdd(Hacc, Hw);
}

// ---------------------------------------------------------------------------
// fp32 W1..W5 -> bf16, concatenated into ws
// ---------------------------------------------------------------------------
__global__ void convert_weights(const float* __restrict__ W1, const float* __restrict__ W2,
                                const float* __restrict__ W3, const float* __restrict__ W4,
                                const float* __restrict__ W5, unsigned short* __restrict__ out)
{
    constexpr int s1 = 784 * 256, s2 = 256 * 128, s3 = 128 * 128, s4 = 128 * 128, s5 = 128 * 32;
    int idx = blockIdx.x * 256 + threadIdx.x;
    if (idx >= s1 + s2 + s3 + s4 + s5) return;
    float v;
    if      (idx < s1)                v = W1[idx];
    else if (idx < s1 + s2)           v = W2[idx - s1];
    else if (idx < s1 + s2 + s3)      v = W3[idx - s1 - s2];
    else if (idx < s1 + s2 + s3 + s4) v = W4[idx - s1 - s2 - s3];
    else                              v = W5[idx - s1 - s2 - s3 - s4];
    out[idx] = f2bf_bits(v);
}

// ---------------------------------------------------------------------------
// Layer 6: out = log_softmax(relu(X @ W6^T + b6)); X bf16 [B,32], one thr/row.
// Block 0 also writes the 5 entropy means (H complete: L5 precedes in-stream).
// ---------------------------------------------------------------------------
__global__ __launch_bounds__(256) void layer6_kernel(
    const unsigned short* __restrict__ Xb, const float* __restrict__ W,
    const float* __restrict__ b, float* __restrict__ out,
    const float* __restrict__ Hacc, float* __restrict__ out_tail)
{
    __shared__ float Wl[320];
    __shared__ float bl[10];
    const int t = threadIdx.x;
    for (int i = t; i < 320; i += 256) Wl[i] = W[i];
    if (t < 10) bl[t] = b[t];
    if (blockIdx.x == 0 && t < 5) out_tail[t] = Hacc[t] * (1.0f / 65536.0f);
    __syncthreads();

    const size_t row = (size_t)blockIdx.x * 256 + t;
    float x[32];
    const uint4* xp = (const uint4*)(Xb + row * 32);
    #pragma unroll
    for (int i = 0; i < 4; i++) {
        uint4 v = xp[i];
        unsigned u[4] = {v.x, v.y, v.z, v.w};
        #pragma unroll
        for (int j = 0; j < 4; j++) {
            x[8 * i + 2 * j]     = bf2f((unsigned short)(u[j] & 0xffffu));
            x[8 * i + 2 * j + 1] = bf2f((unsigned short)(u[j] >> 16));
        }
    }

    float z[10];
    float m = -1e30f;
    #pragma unroll
    for (int j = 0; j < 10; j++) {
        float s = bl[j];
        #pragma unroll
        for (int k = 0; k < 32; k++) s = fmaf(x[k], Wl[j * 32 + k], s);
        z[j] = fmaxf(s, 0.0f);
        m = fmaxf(m, z[j]);
    }
    float se = 0.0f;
    #pragma unroll
    for (int j = 0; j < 10; j++) se += __expf(z[j] - m);
    float ls = __logf(se);
    float* op = out + row * 10;
    #pragma unroll
    for (int j = 0; j < 10; j++) op[j] = z[j] - m - ls;
}

// ---------------------------------------------------------------------------
extern "C" void kernel_launch(void* const* d_in, const int* in_sizes, int n_in,
                              void* d_out, int out_size, void* d_ws, size_t ws_size,
                              hipStream_t stream)
{
    const float* x  = (const float*)d_in[0];
    const float* W1 = (const float*)d_in[1];  const float* b1 = (const float*)d_in[2];
    const float* W2 = (const float*)d_in[3];  const float* b2 = (const float*)d_in[4];
    const float* W3 = (const float*)d_in[5];  const float* b3 = (const float*)d_in[6];
    const float* W4 = (const float*)d_in[7];  const float* b4 = (const float*)d_in[8];
    const float* W5 = (const float*)d_in[9];  const float* b5 = (const float*)d_in[10];
    const float* W6 = (const float*)d_in[11]; const float* b6 = (const float*)d_in[12];
    float* out = (float*)d_out;

    constexpr int B = 65536;
    char* ws = (char*)d_ws;
    float* H = (float*)ws;                                  // 5 floats @ 0
    unsigned short* Wcat = (unsigned short*)(ws + 256);
    unsigned short* W1b = Wcat;                              // 784*256
    unsigned short* W2b = W1b + 784 * 256;                   // 256*128
    unsigned short* W3b = W2b + 256 * 128;                   // 128*128
    unsigned short* W4b = W3b + 128 * 128;                   // 128*128
    unsigned short* W5b = W4b + 128 * 128;                   // 128*32
    unsigned short* bufA = (unsigned short*)(ws + 541184);             // B*256 bf16
    unsigned short* bufB = (unsigned short*)(ws + 541184 + (size_t)B * 256 * 2);

    hipMemsetAsync(H, 0, 5 * sizeof(float), stream);
    convert_weights<<<1056, 256, 0, stream>>>(W1, W2, W3, W4, W5, Wcat);

    layer_mfma<784, 256, true , 3><<<B / 64, 256, 0, stream>>>(x,    W1b, b1, bufA, H + 0);
    layer_mfma<256, 128, false, 4><<<B / 64, 256, 0, stream>>>(bufA, W2b, b2, bufB, H + 1);
    layer_mfma<128, 128, false, 4><<<B / 64, 256, 0, stream>>>(bufB, W3b, b3, bufA, H + 2);
    layer_mfma<128, 128, false, 4><<<B / 64, 256, 0, stream>>>(bufA, W4b, b4, bufB, H + 3);
    layer_mfma<128,  32, false, 4><<<B / 64, 256, 0, stream>>>(bufB, W5b, b5, bufA, H + 4);

    layer6_kernel<<<B / 256, 256, 0, stream>>>(bufA, W6, b6, out, H, out + (size_t)B * 10);
}

// Round 4
// 555.287 us; speedup vs baseline: 1.6273x; 1.2189x over previous
//
#include <hip/hip_runtime.h>
#include <hip/hip_bf16.h>
#include <math.h>

#define ALPHA 0.01f

typedef __bf16 bf16x8 __attribute__((ext_vector_type(8)));
typedef float  floatx4 __attribute__((ext_vector_type(4)));

static __device__ __forceinline__ unsigned short f2bf_bits(float f) {
    return __builtin_bit_cast(unsigned short, (__bf16)f);   // RNE
}
static __device__ __forceinline__ float bf2f(unsigned short u) {
    return __builtin_bit_cast(float, (unsigned)u << 16);    // exact
}

// 16-lane (DPP row) reductions — pure VALU, no LDS traffic.
template <int CTRL>
static __device__ __forceinline__ float dppmov(float x) {
    int r = __builtin_amdgcn_update_dpp(0, __builtin_bit_cast(int, x), CTRL, 0xf, 0xf, false);
    return __builtin_bit_cast(float, r);
}
static __device__ __forceinline__ float red16min(float x) {
    x = fminf(x, dppmov<0x121>(x)); x = fminf(x, dppmov<0x122>(x));
    x = fminf(x, dppmov<0x124>(x)); x = fminf(x, dppmov<0x128>(x));
    return x;
}
static __device__ __forceinline__ float red16max(float x) {
    x = fmaxf(x, dppmov<0x121>(x)); x = fmaxf(x, dppmov<0x122>(x));
    x = fmaxf(x, dppmov<0x124>(x)); x = fmaxf(x, dppmov<0x128>(x));
    return x;
}
static __device__ __forceinline__ float red16sum(float x) {
    x += dppmov<0x121>(x); x += dppmov<0x122>(x);
    x += dppmov<0x124>(x); x += dppmov<0x128>(x);
    return x;
}

// ---------------------------------------------------------------------------
// MFMA layer: Y(bf16) = leaky_relu(X @ W^T + b); per-row histogram entropy
// (bins = DOUT) summed into *Hacc.
//
// Block = 256 thr (4 waves) x 128 rows. Wave w owns rows [w*32, w*32+32)
// (2 A-frags rt=0,1) x full DOUT. A-fragments are loaded DIRECTLY from
// global (A-layout = 16 contiguous bytes of a row) — zero LDS for A.
// W is staged in LDS in FRAGMENT-MAJOR order: 16B slot index
// (ktl*CTN+ct)*64 + lane  ->  B-frag read is base + lane*16: conflict-free.
// Staging writes are thread-linear: conflict-free. L1 stages W in 64 KB
// K-chunks (7 chunks); L2-L5 stage whole W once (1 barrier pair).
// Entropy runs from accumulator registers; 16-lane reductions via DPP
// row_ror; histogram = per-(wave,quad) packed u16 counts, word = b&(D/2-1)
// so adjacent hot bins (leaky-relu negatives cluster at bins 0-2) hit
// different words/banks; +1 word pad decorrelates quads across banks.
// ---------------------------------------------------------------------------
template <int DIN, int DOUT, bool XF32, int CHUNK_KT>
__global__ __launch_bounds__(256, 2) void layer_mfma(
    const void* __restrict__ Xin, const unsigned short* __restrict__ Wb,
    const float* __restrict__ bias, unsigned short* __restrict__ Y,
    float* __restrict__ Hacc)
{
    constexpr int CTN     = DOUT / 16;
    constexpr int KTN     = (DIN + 31) / 32;
    constexpr int NCF     = KTN / CHUNK_KT;        // full chunks
    constexpr int TAILKT  = KTN % CHUNK_KT;        // trailing ktiles (L1: 1)
    constexpr int CHUNK_K = CHUNK_KT * 32;
    constexpr int HALF    = DOUT / 2;
    constexpr int LOG2D   = (DOUT == 256) ? 8 : (DOUT == 128) ? 7 : 5;
    constexpr float LOGB  = (DOUT == 256) ? 5.54517744f
                          : (DOUT == 128) ? 4.85203026f : 3.46573590f;
    constexpr int NST     = DOUT * CHUNK_K / 8 / 256;   // 16B chunks per thread
    static_assert(DOUT % 32 == 0 && DOUT <= 256, "DOUT");

    __shared__ __align__(16) unsigned short Wl[DOUT * CHUNK_K];
    __shared__ unsigned int counts[16][HALF + 1];

    const int t      = threadIdx.x;
    const int lane   = t & 63;
    const int lane16 = lane & 15;
    const int q      = lane >> 4;
    const int w      = t >> 6;
    const int row0   = blockIdx.x * 128;
    const int arow0  = row0 + w * 32 + lane16;   // +16 for rt=1

    float biasr[CTN];
    #pragma unroll
    for (int ct = 0; ct < CTN; ct++) biasr[ct] = bias[ct * 16 + lane16];

    floatx4 acc[2][CTN];
    #pragma unroll
    for (int rt = 0; rt < 2; rt++)
        #pragma unroll
        for (int ct = 0; ct < CTN; ct++) acc[rt][ct] = (floatx4)(0.0f);

    // ---- stage one W K-chunk into fragment-major LDS (thread-linear slots)
    auto stage = [&](int k0c) {
        #pragma unroll
        for (int i = 0; i < NST; i++) {
            int s   = t + i * 256;              // 16B slot index
            int ktl = s / (CTN * 64);
            int ct  = (s / 64) % CTN;
            int qq  = (s >> 4) & 3;
            int r15 = s & 15;
            int r   = ct * 16 + r15;
            int k   = k0c + ktl * 32 + qq * 8;
            uint4 v = make_uint4(0u, 0u, 0u, 0u);
            if (k + 8 <= DIN) v = *(const uint4*)(Wb + (size_t)r * DIN + k);
            *(uint4*)(Wl + (size_t)s * 8) = v;
        }
    };

    // ---- one 32-wide k-tile: direct-global A frags + LDS B frags + MFMA
    auto ktile = [&](int ktl, int kg, bool chk) {
        bf16x8 a[2];
        #pragma unroll
        for (int rt = 0; rt < 2; rt++) {
            if constexpr (XF32) {
                const float* p = (const float*)Xin
                               + (size_t)(arow0 + rt * 16) * DIN + kg + q * 8;
                float4 v0 = make_float4(0.f, 0.f, 0.f, 0.f), v1 = v0;
                if (!chk || (kg + q * 8 + 8 <= DIN)) {
                    v0 = *(const float4*)p;
                    v1 = *(const float4*)(p + 4);
                }
                uint4 pk;
                pk.x = (unsigned)f2bf_bits(v0.x) | ((unsigned)f2bf_bits(v0.y) << 16);
                pk.y = (unsigned)f2bf_bits(v0.z) | ((unsigned)f2bf_bits(v0.w) << 16);
                pk.z = (unsigned)f2bf_bits(v1.x) | ((unsigned)f2bf_bits(v1.y) << 16);
                pk.w = (unsigned)f2bf_bits(v1.z) | ((unsigned)f2bf_bits(v1.w) << 16);
                a[rt] = __builtin_bit_cast(bf16x8, pk);
            } else {
                a[rt] = *(const bf16x8*)((const unsigned short*)Xin
                        + (size_t)(arow0 + rt * 16) * DIN + kg + q * 8);
            }
        }
        const unsigned short* wbase = Wl + (size_t)(ktl * CTN * 64 + lane) * 8;
        #pragma unroll
        for (int ct = 0; ct < CTN; ct++) {
            bf16x8 bw = *(const bf16x8*)(wbase + (size_t)ct * 512);
            acc[0][ct] = __builtin_amdgcn_mfma_f32_16x16x32_bf16(a[0], bw, acc[0][ct], 0, 0, 0);
            acc[1][ct] = __builtin_amdgcn_mfma_f32_16x16x32_bf16(a[1], bw, acc[1][ct], 0, 0, 0);
        }
    };

    for (int c = 0; c < NCF; c++) {
        __syncthreads();
        stage(c * CHUNK_K);
        __syncthreads();
        #pragma unroll
        for (int ktl = 0; ktl < CHUNK_KT; ktl++)
            ktile(ktl, c * CHUNK_K + ktl * 32, false);
    }
    if constexpr (TAILKT > 0) {
        __syncthreads();
        stage(NCF * CHUNK_K);
        __syncthreads();
        #pragma unroll
        for (int ktl = 0; ktl < TAILKT; ktl++)
            ktile(ktl, NCF * CHUNK_K + ktl * 32, true);
    }

    // ---- epilogue: bias + leaky_relu in registers; direct bf16 stores
    #pragma unroll
    for (int rt = 0; rt < 2; rt++)
        #pragma unroll
        for (int ct = 0; ct < CTN; ct++) {
            #pragma unroll
            for (int reg = 0; reg < 4; reg++) {
                float v = acc[rt][ct][reg] + biasr[ct];
                v = v > 0.0f ? v : ALPHA * v;
                acc[rt][ct][reg] = v;
                Y[(size_t)(row0 + w * 32 + rt * 16 + q * 4 + reg) * DOUT
                  + ct * 16 + lane16] = f2bf_bits(v);
            }
        }

    // ---- entropy: quad q processes rows rt*16 + q*4 + reg (8 slots)
    unsigned int* cc = counts[w * 4 + q];
    float Hq = 0.0f;
    #pragma unroll
    for (int rt = 0; rt < 2; rt++) {
        #pragma unroll
        for (int reg = 0; reg < 4; reg++) {
            float mn = acc[rt][0][reg], mx = mn;
            #pragma unroll
            for (int ct = 1; ct < CTN; ct++) {
                mn = fminf(mn, acc[rt][ct][reg]);
                mx = fmaxf(mx, acc[rt][ct][reg]);
            }
            mn = red16min(mn);
            mx = red16max(mx);
            float wdt = mx - mn;
            float scale = (float)DOUT / (wdt > 0.0f ? wdt : 1.0f);

            #pragma unroll
            for (int i = 0; i < DOUT / 32; i++) cc[lane16 + 16 * i] = 0u;
            // DS ops from one wave complete in order: zeros -> atomics -> reads

            #pragma unroll
            for (int ct = 0; ct < CTN; ct++) {
                int b = (int)((acc[rt][ct][reg] - mn) * scale);
                b = b < (DOUT - 1) ? b : (DOUT - 1);
                atomicAdd(&cc[b & (HALF - 1)],
                          1u << (((b >> (LOG2D - 1)) & 1) << 4));
            }

            float s = 0.0f;
            #pragma unroll
            for (int i = 0; i < DOUT / 32; i++) {
                unsigned int word = cc[lane16 + 16 * i];
                int c0 = (int)(word & 0xffffu), c1 = (int)(word >> 16);
                if (c0 > 0) { float p = (float)c0 * (1.0f / (float)DOUT); s += p * __logf(p); }
                if (c1 > 0) { float p = (float)c1 * (1.0f / (float)DOUT); s += p * __logf(p); }
            }
            s = red16sum(s);
            Hq += LOGB - s;
        }
    }
    Hq += __shfl_xor(Hq, 16, 64);
    Hq += __shfl_xor(Hq, 32, 64);
    if (lane == 0) atomicAdd(Hacc, Hq);
}

// ---------------------------------------------------------------------------
// fp32 W1..W5 -> bf16, concatenated into ws
// ---------------------------------------------------------------------------
__global__ void convert_weights(const float* __restrict__ W1, const float* __restrict__ W2,
                                const float* __restrict__ W3, const float* __restrict__ W4,
                                const float* __restrict__ W5, unsigned short* __restrict__ out)
{
    constexpr int s1 = 784 * 256, s2 = 256 * 128, s3 = 128 * 128, s4 = 128 * 128, s5 = 128 * 32;
    int idx = blockIdx.x * 256 + threadIdx.x;
    if (idx >= s1 + s2 + s3 + s4 + s5) return;
    float v;
    if      (idx < s1)                v = W1[idx];
    else if (idx < s1 + s2)           v = W2[idx - s1];
    else if (idx < s1 + s2 + s3)      v = W3[idx - s1 - s2];
    else if (idx < s1 + s2 + s3 + s4) v = W4[idx - s1 - s2 - s3];
    else                              v = W5[idx - s1 - s2 - s3 - s4];
    out[idx] = f2bf_bits(v);
}

// ---------------------------------------------------------------------------
// Layer 6: out = log_softmax(relu(X @ W6^T + b6)); X bf16 [B,32], one thr/row.
// Block 0 also writes the 5 entropy means (H complete: L5 precedes in-stream).
// ---------------------------------------------------------------------------
__global__ __launch_bounds__(256) void layer6_kernel(
    const unsigned short* __restrict__ Xb, const float* __restrict__ W,
    const float* __restrict__ b, float* __restrict__ out,
    const float* __restrict__ Hacc, float* __restrict__ out_tail)
{
    __shared__ float Wl[320];
    __shared__ float bl[10];
    const int t = threadIdx.x;
    for (int i = t; i < 320; i += 256) Wl[i] = W[i];
    if (t < 10) bl[t] = b[t];
    if (blockIdx.x == 0 && t < 5) out_tail[t] = Hacc[t] * (1.0f / 65536.0f);
    __syncthreads();

    const size_t row = (size_t)blockIdx.x * 256 + t;
    float x[32];
    const uint4* xp = (const uint4*)(Xb + row * 32);
    #pragma unroll
    for (int i = 0; i < 4; i++) {
        uint4 v = xp[i];
        unsigned u[4] = {v.x, v.y, v.z, v.w};
        #pragma unroll
        for (int j = 0; j < 4; j++) {
            x[8 * i + 2 * j]     = bf2f((unsigned short)(u[j] & 0xffffu));
            x[8 * i + 2 * j + 1] = bf2f((unsigned short)(u[j] >> 16));
        }
    }

    float z[10];
    float m = -1e30f;
    #pragma unroll
    for (int j = 0; j < 10; j++) {
        float s = bl[j];
        #pragma unroll
        for (int k = 0; k < 32; k++) s = fmaf(x[k], Wl[j * 32 + k], s);
        z[j] = fmaxf(s, 0.0f);
        m = fmaxf(m, z[j]);
    }
    float se = 0.0f;
    #pragma unroll
    for (int j = 0; j < 10; j++) se += __expf(z[j] - m);
    float ls = __logf(se);
    float* op = out + row * 10;
    #pragma unroll
    for (int j = 0; j < 10; j++) op[j] = z[j] - m - ls;
}

// ---------------------------------------------------------------------------
extern "C" void kernel_launch(void* const* d_in, const int* in_sizes, int n_in,
                              void* d_out, int out_size, void* d_ws, size_t ws_size,
                              hipStream_t stream)
{
    const float* x  = (const float*)d_in[0];
    const float* W1 = (const float*)d_in[1];  const float* b1 = (const float*)d_in[2];
    const float* W2 = (const float*)d_in[3];  const float* b2 = (const float*)d_in[4];
    const float* W3 = (const float*)d_in[5];  const float* b3 = (const float*)d_in[6];
    const float* W4 = (const float*)d_in[7];  const float* b4 = (const float*)d_in[8];
    const float* W5 = (const float*)d_in[9];  const float* b5 = (const float*)d_in[10];
    const float* W6 = (const float*)d_in[11]; const float* b6 = (const float*)d_in[12];
    float* out = (float*)d_out;

    constexpr int B = 65536;
    char* ws = (char*)d_ws;
    float* H = (float*)ws;                                  // 5 floats @ 0
    unsigned short* Wcat = (unsigned short*)(ws + 256);
    unsigned short* W1b = Wcat;                              // 784*256
    unsigned short* W2b = W1b + 784 * 256;                   // 256*128
    unsigned short* W3b = W2b + 256 * 128;                   // 128*128
    unsigned short* W4b = W3b + 128 * 128;                   // 128*128
    unsigned short* W5b = W4b + 128 * 128;                   // 128*32
    unsigned short* bufA = (unsigned short*)(ws + 541184);             // B*256 bf16
    unsigned short* bufB = (unsigned short*)(ws + 541184 + (size_t)B * 256 * 2);

    hipMemsetAsync(H, 0, 5 * sizeof(float), stream);
    convert_weights<<<1056, 256, 0, stream>>>(W1, W2, W3, W4, W5, Wcat);

    layer_mfma<784, 256, true , 4><<<B / 128, 256, 0, stream>>>(x,    W1b, b1, bufA, H + 0);
    layer_mfma<256, 128, false, 8><<<B / 128, 256, 0, stream>>>(bufA, W2b, b2, bufB, H + 1);
    layer_mfma<128, 128, false, 4><<<B / 128, 256, 0, stream>>>(bufB, W3b, b3, bufA, H + 2);
    layer_mfma<128, 128, false, 4><<<B / 128, 256, 0, stream>>>(bufA, W4b, b4, bufB, H + 3);
    layer_mfma<128,  32, false, 4><<<B / 128, 256, 0, stream>>>(bufB, W5b, b5, bufA, H + 4);

    layer6_kernel<<<B / 256, 256, 0, stream>>>(bufA, W6, b6, out, H, out + (size_t)B * 10);
}